// Round 9
// baseline (839.241 us; speedup 1.0000x reference)
//
#include <hip/hip_runtime.h>

#define XY 65160     // 360*181
#define NI 96
#define NO 96
#define NK 8
#define TNX 64       // xy per block tile
#define NT 1019      // ceil(XY/64)

typedef __attribute__((ext_vector_type(8))) short short8;
typedef __attribute__((ext_vector_type(4))) float floatx4;

union FragU { short8 v; unsigned u[4]; };

typedef __attribute__((address_space(3))) unsigned       lds_u32;
typedef const __attribute__((address_space(1))) unsigned g_u32;

// hardware packed f32x2 -> bf16x2 (RNE)
static __device__ __forceinline__ unsigned cvt_pk(float lo, float hi) {
    unsigned r;
    asm("v_cvt_pk_bf16_f32 %0, %1, %2" : "=v"(r) : "v"(lo), "v"(hi));
    return r;
}

__global__ __launch_bounds__(512, 4) void cmult_kernel(
    const float* __restrict__ inp, const float* __restrict__ weight,
    const float* __restrict__ bias, float* __restrict__ out)
{
    // input tile staged direct-to-LDS as fp32: [i][lxy] float2, 48 KB (linear, no pad)
    __shared__ float atile[NI * TNX * 2];
    __shared__ float2 blds[NO];

    const int tid  = threadIdx.x;
    const int lane = tid & 63;
    const int wave = tid >> 6;       // 8 waves
    const int h    = wave & 1;       // o-half: m = 3h + mm
    const int g    = wave >> 1;      // xy group (16 xy each, 4 groups = 64 xy)
    const int k    = blockIdx.y;
    const int l15  = lane & 15;
    const int quad = lane >> 4;

    const float* inpk = inp    + (size_t)k * NI * XY * 2;
    const float* wk   = weight + (size_t)k * NI * NO * 2;

    if (tid < NO) blds[tid] = *reinterpret_cast<const float2*>(bias + ((size_t)k * NO + tid) * 2);

    // ---- weights -> registers, packed bf16 A-fragments (once per kernel) ----
    // fragment (s,mm): m = 3h+mm; lane holds o = 16m + l15; u[t] covers i = 16s + 4*quad + t
    FragU wfr[6][3];
    #pragma unroll
    for (int s = 0; s < 6; ++s) {
        #pragma unroll
        for (int mm = 0; mm < 3; ++mm) {
            int m = 3 * h + mm;
            #pragma unroll
            for (int t = 0; t < 4; ++t) {
                int i = 16 * s + 4 * quad + t;
                float2 w = *reinterpret_cast<const float2*>(wk + ((size_t)i * NO + 16 * m + l15) * 2);
                wfr[s][mm].u[t] = cvt_pk(w.x, w.y);   // (wr, wi) plain
            }
        }
    }

    for (int tidx = blockIdx.x; tidx < NT; tidx += gridDim.x) {
        const int x0 = tidx * TNX;

        __syncthreads();   // all prev-tile ds_reads done -> LDS free to overwrite

        // ---- async stage: 48 global_load_lds x 1KB; instr n covers rows {2n, 2n+1} ----
        #pragma unroll
        for (int j = 0; j < 6; ++j) {
            int n   = wave * 6 + j;
            int row = 2 * n + (lane >> 5);
            int xy  = x0 + (lane & 31) * 2;
            if (xy > XY - 2) xy = XY - 2;                  // per-lane clamp (src is per-lane)
            const float* gsrc = inpk + ((size_t)row * XY + xy) * 2;
            __builtin_amdgcn_global_load_lds(
                (g_u32*)gsrc, (lds_u32*)atile + n * 256, 16, 0, 0);
        }

        __syncthreads();   // vmcnt drain + barrier: tile fully staged

        floatx4 accR[3], accI[3];
        #pragma unroll
        for (int mm = 0; mm < 3; ++mm) {
            accR[mm] = (floatx4){0.f,0.f,0.f,0.f};
            accI[mm] = (floatx4){0.f,0.f,0.f,0.f};
        }

        #pragma unroll
        for (int s = 0; s < 6; ++s) {
            // B variants: bN = (ar,-ai) -> real chain; bS = (ai,ar) -> imag chain
            FragU bN, bS;
            #pragma unroll
            for (int t = 0; t < 4; ++t) {
                int i = 16 * s + 4 * quad + t;
                float2 a = *reinterpret_cast<const float2*>(atile + ((size_t)i * TNX + g * 16 + l15) * 2);
                unsigned p = cvt_pk(a.x, a.y);            // (ar, ai)
                bN.u[t] = p ^ 0x80000000u;                // (ar, -ai)
                bS.u[t] = (p >> 16) | (p << 16);          // (ai,  ar)
            }
            #pragma unroll
            for (int mm = 0; mm < 3; ++mm) {
                accR[mm] = __builtin_amdgcn_mfma_f32_16x16x32_bf16(wfr[s][mm].v, bN.v, accR[mm], 0, 0, 0);
                accI[mm] = __builtin_amdgcn_mfma_f32_16x16x32_bf16(wfr[s][mm].v, bS.v, accI[mm], 0, 0, 0);
            }
        }

        // ---- epilogue: D col = lane&15 (xy), row = quad*4 + r (o within 16-tile) ----
        int xy = x0 + g * 16 + l15;
        if (xy < XY) {
            #pragma unroll
            for (int mm = 0; mm < 3; ++mm) {
                #pragma unroll
                for (int r = 0; r < 4; ++r) {
                    int o = 16 * (3 * h + mm) + 4 * quad + r;
                    float2 b = blds[o];
                    float2 ov;
                    ov.x = accR[mm][r] + b.x;
                    ov.y = accI[mm][r] + b.y;
                    *reinterpret_cast<float2*>(out + ((size_t)(k * NO + o) * XY + xy) * 2) = ov;
                }
            }
        }
    }
}

extern "C" void kernel_launch(void* const* d_in, const int* in_sizes, int n_in,
                              void* d_out, int out_size, void* d_ws, size_t ws_size,
                              hipStream_t stream)
{
    const float* inp    = (const float*)d_in[0];
    const float* weight = (const float*)d_in[1];
    const float* bias   = (const float*)d_in[2];
    float* out = (float*)d_out;

    dim3 grid(128, NK), block(512);
    hipLaunchKernelGGL(cmult_kernel, grid, block, 0, stream, inp, weight, bias, out);
}